// Round 3
// baseline (562.987 us; speedup 1.0000x reference)
//
#include <hip/hip_runtime.h>
#include <hip/hip_bf16.h>
#include <stdint.h>

static constexpr int N_ = 16384;
static constexpr int D_ = 2048;
static constexpr float SCALE_R = 1.0f / 16.0f;            // 1/sqrt(HD=256)
static constexpr float SCALE_W = 0.02209708691207961f;    // 1/sqrt(D=2048)

typedef __bf16 bf16x8 __attribute__((ext_vector_type(8)));
typedef float f32x4 __attribute__((ext_vector_type(4)));

__device__ __forceinline__ unsigned short f2bf(float f) {
  unsigned int u = __float_as_uint(f);
  unsigned int r = (u + 0x7fff + ((u >> 16) & 1)) >> 16;  // RNE
  return (unsigned short)r;
}

__device__ __forceinline__ void lds_load16(void* lds, const void* g) {
  __builtin_amdgcn_global_load_lds(
      (const __attribute__((address_space(1))) uint32_t*)(uintptr_t)g,
      (__attribute__((address_space(3))) uint32_t*)(uint32_t)(uintptr_t)lds,
      16, 0, 0);
}

// ---- K1: k = memory@Wrk.T, v = memory@Wrv.T, wq = memory@Wwq.T  (each [8][2048])
__global__ __launch_bounds__(256) void k_kvwq(
    const float* __restrict__ mem, const float* __restrict__ wrk,
    const float* __restrict__ wrv, const float* __restrict__ wwq,
    float* __restrict__ kbuf, float* __restrict__ vbuf, float* __restrict__ wqbuf) {
  int gw = (blockIdx.x * 256 + threadIdx.x) >> 6;  // 0..6143
  int lane = threadIdx.x & 63;
  int which = gw >> 11;
  int j = gw & 2047;
  const float* W = which == 0 ? wrk : (which == 1 ? wrv : wwq);
  float* O = which == 0 ? kbuf : (which == 1 ? vbuf : wqbuf);
  const f32x4* Wrow = (const f32x4*)(W + (size_t)j * D_);
  const f32x4* M4 = (const f32x4*)mem;
  float acc[8];
#pragma unroll
  for (int kk = 0; kk < 8; ++kk) acc[kk] = 0.f;
#pragma unroll
  for (int t = 0; t < 8; ++t) {
    f32x4 w4 = Wrow[lane + 64 * t];
#pragma unroll
    for (int kk = 0; kk < 8; ++kk) {
      f32x4 m4 = M4[kk * 512 + lane + 64 * t];
      acc[kk] += w4[0] * m4[0] + w4[1] * m4[1] + w4[2] * m4[2] + w4[3] * m4[3];
    }
  }
#pragma unroll
  for (int off = 1; off < 64; off <<= 1)
#pragma unroll
    for (int kk = 0; kk < 8; ++kk) acc[kk] += __shfl_xor(acc[kk], off, 64);
  if (lane == 0) {
#pragma unroll
    for (int kk = 0; kk < 8; ++kk) O[kk * D_ + j] = acc[kk];
  }
}

// ---- K2: PRT[80][2048] fp32: rows 0..63 = P (scaled 1/16), rows 64..71 = R
__global__ __launch_bounds__(256) void k_pr(
    const float* __restrict__ wrq, const float* __restrict__ wwk,
    const float* __restrict__ kbuf, const float* __restrict__ wqbuf,
    float* __restrict__ PRT) {
  int b = blockIdx.x;
  int tid = threadIdx.x;
  if (b < 64) {
    int ic = b >> 3, h = b & 7;
    int i = ic * 256 + tid;
    float acc[8];
#pragma unroll
    for (int kk = 0; kk < 8; ++kk) acc[kk] = 0.f;
    for (int jj = 0; jj < 256; ++jj) {
      int j = h * 256 + jj;
      float wv = wrq[(size_t)j * D_ + i];
#pragma unroll
      for (int kk = 0; kk < 8; ++kk) acc[kk] += wv * kbuf[kk * D_ + j];
    }
#pragma unroll
    for (int kk = 0; kk < 8; ++kk) PRT[(h * 8 + kk) * D_ + i] = acc[kk] * SCALE_R;
  } else {
    int bb = b - 64;
    int ic = bb >> 3, jc = bb & 7;
    int i = ic * 256 + tid;
    float acc[8];
#pragma unroll
    for (int kk = 0; kk < 8; ++kk) acc[kk] = 0.f;
    for (int jj = 0; jj < 256; ++jj) {
      int j = jc * 256 + jj;
      float wv = wwk[(size_t)j * D_ + i];
#pragma unroll
      for (int kk = 0; kk < 8; ++kk) acc[kk] += wv * wqbuf[kk * D_ + j];
    }
#pragma unroll
    for (int kk = 0; kk < 8; ++kk) atomicAdd(&PRT[(64 + kk) * D_ + i], acc[kk] * SCALE_W);
  }
}

// ---- W' = gamma ⊙ Wout rows -> bf16 (one row per block)
__global__ __launch_bounds__(256) void k_cvtw(const float* __restrict__ wro,
                                              const float* __restrict__ gamma,
                                              unsigned short* __restrict__ wp) {
  int j = blockIdx.x;
  int d = threadIdx.x * 8;
  const float* src = wro + (size_t)j * D_ + d;
  f32x4 a = *(const f32x4*)src, b = *(const f32x4*)(src + 4);
  f32x4 g0 = *(const f32x4*)(gamma + d), g1 = *(const f32x4*)(gamma + d + 4);
  ushort4 o0, o1;
  o0.x = f2bf(a[0] * g0[0]); o0.y = f2bf(a[1] * g0[1]);
  o0.z = f2bf(a[2] * g0[2]); o0.w = f2bf(a[3] * g0[3]);
  o1.x = f2bf(b[0] * g1[0]); o1.y = f2bf(b[1] * g1[1]);
  o1.z = f2bf(b[2] * g1[2]); o1.w = f2bf(b[3] * g1[3]);
  unsigned short* dst = wp + (size_t)j * D_ + d;
  *(ushort4*)dst = o0;
  *(ushort4*)(dst + 4) = o1;
}

// ---- c1[j] = sum_d gamma[d]*W[j][d], c2[j] = sum_d beta[d]*W[j][d]
__global__ __launch_bounds__(256) void k_wsum(const float* __restrict__ wro,
                                              const float* __restrict__ gamma,
                                              const float* __restrict__ beta,
                                              float* __restrict__ c1, float* __restrict__ c2) {
  int wave = threadIdx.x >> 6, lane = threadIdx.x & 63;
  int j = blockIdx.x * 4 + wave;
  const float* row = wro + (size_t)j * D_;
  float s1 = 0.f, s2 = 0.f;
#pragma unroll
  for (int t = 0; t < 8; ++t) {
    int d = t * 256 + lane * 4;
    f32x4 w = *(const f32x4*)(row + d);
    f32x4 g = *(const f32x4*)(gamma + d);
    f32x4 b = *(const f32x4*)(beta + d);
    s1 += w[0] * g[0] + w[1] * g[1] + w[2] * g[2] + w[3] * g[3];
    s2 += w[0] * b[0] + w[1] * b[1] + w[2] * b[2] + w[3] * b[3];
  }
#pragma unroll
  for (int off = 1; off < 64; off <<= 1) {
    s1 += __shfl_xor(s1, off, 64);
    s2 += __shfl_xor(s2, off, 64);
  }
  if (lane == 0) { c1[j] = s1; c2[j] = s2; }
}

// ---- K3: fused MFMA S-GEMM + in-reg PER-HEAD softmax + ro + (raw ro, mu, rstd) + u-partials
__global__ __launch_bounds__(256) void k_main(
    const float* __restrict__ hidden, const float* __restrict__ PRT,
    const float* __restrict__ vbuf,
    unsigned short* __restrict__ Xhat, float* __restrict__ mu_out,
    float* __restrict__ rstd_out,
    float* __restrict__ upart, float* __restrict__ Zpart) {
  __shared__ unsigned short Ah[2][64 * 64];   // 16 KB, XOR-swizzled bf16 hidden tile
  __shared__ unsigned short Bh[2][80 * 64];   // 20 KB, XOR-swizzled bf16 PRT tile
  __shared__ unsigned short attnL[64 * 64];   // 8 KB bf16 attn
  __shared__ float e8lds[64][8];              // 2 KB
  const int tid = threadIdx.x;
  const int row0 = blockIdx.x * 64;
  const int wave = tid >> 6, lane = tid & 63;
  const int fl = lane & 15, fk = lane >> 4;
  const int ar = tid >> 2, acg = tid & 3;     // A staging: row, 16-col group

  f32x4 sA0[4], sB0[5], sA1[4], sB1[5];

  auto loadAB = [&](f32x4* a, f32x4* b, int t) {
    const float* srcA = hidden + (size_t)(row0 + ar) * D_ + t * 64 + acg * 16;
#pragma unroll
    for (int q = 0; q < 4; ++q) a[q] = *(const f32x4*)(srcA + q * 4);
#pragma unroll
    for (int p = 0; p < 5; ++p) {
      int e = p * 256 + tid;
      int rB = e >> 4, c4 = e & 15;
      b[p] = *(const f32x4*)(PRT + (size_t)rB * D_ + t * 64 + c4 * 4);
    }
  };
  auto writeAB = [&](int buf, f32x4* a, f32x4* b) {
#pragma unroll
    for (int hh = 0; hh < 2; ++hh) {
      f32x4 x = a[hh * 2], y = a[hh * 2 + 1];
      ushort4 o0 = {f2bf(x[0]), f2bf(x[1]), f2bf(x[2]), f2bf(x[3])};
      ushort4 o1 = {f2bf(y[0]), f2bf(y[1]), f2bf(y[2]), f2bf(y[3])};
      int idx = (ar * 64 + acg * 16 + hh * 8) ^ ((ar & 7) << 3);
      *(ushort4*)&Ah[buf][idx] = o0;
      *(ushort4*)&Ah[buf][idx + 4] = o1;
    }
#pragma unroll
    for (int p = 0; p < 5; ++p) {
      int e = p * 256 + tid;
      int rB = e >> 4, c4 = e & 15;
      ushort4 o = {f2bf(b[p][0]), f2bf(b[p][1]), f2bf(b[p][2]), f2bf(b[p][3])};
      int idx = (rB * 64 + c4 * 4) ^ ((rB & 7) << 3);
      *(ushort4*)&Bh[buf][idx] = o;
    }
  };

  f32x4 acc[5];
#pragma unroll
  for (int n = 0; n < 5; ++n) acc[n] = (f32x4){0.f, 0.f, 0.f, 0.f};

  auto compute = [&](int buf) {
#pragma unroll
    for (int kk = 0; kk < 2; ++kk) {
      int klo = kk * 32 + fk * 8;
      bf16x8 af = *(const bf16x8*)&Ah[buf][((wave * 16 + fl) * 64 + klo) ^ ((fl & 7) << 3)];
#pragma unroll
      for (int n = 0; n < 5; ++n) {
        bf16x8 bf = *(const bf16x8*)&Bh[buf][((n * 16 + fl) * 64 + klo) ^ ((fl & 7) << 3)];
        acc[n] = __builtin_amdgcn_mfma_f32_16x16x32_bf16(af, bf, acc[n], 0, 0, 0);
      }
    }
  };

  loadAB(sA0, sB0, 0);
  loadAB(sA1, sB1, 1);
  for (int t = 0; t < 32; t += 2) {
    writeAB(0, sA0, sB0);
    if (t + 2 < 32) loadAB(sA0, sB0, t + 2);
    __syncthreads();
    compute(0);
    writeAB(1, sA1, sB1);
    if (t + 3 < 32) loadAB(sA1, sB1, t + 3);
    __syncthreads();
    compute(1);
  }

  // ---- in-register PER-HEAD softmax.
  // acc[n][r] = S[row=wave*16+fk*4+r][col=n*16+fl]; head = col>>3 lives in one
  // 8-lane half of one reg n -> reduce with xor 1,2,4 only (stays in the half).
#pragma unroll
  for (int r = 0; r < 4; ++r) {
    int rowl = wave * 16 + fk * 4 + r;
#pragma unroll
    for (int n = 0; n < 4; ++n) {
      float sv = acc[n][r];
      float m = sv;
      m = fmaxf(m, __shfl_xor(m, 1, 64));
      m = fmaxf(m, __shfl_xor(m, 2, 64));
      m = fmaxf(m, __shfl_xor(m, 4, 64));
      float e = __expf(sv - m);
      float ssum = e;
      ssum += __shfl_xor(ssum, 1, 64);
      ssum += __shfl_xor(ssum, 2, 64);
      ssum += __shfl_xor(ssum, 4, 64);
      attnL[rowl * 64 + n * 16 + fl] = f2bf(e / ssum);
    }
    if (fl < 8) e8lds[rowl][fl] = __expf(acc[4][r]);  // write-softmax numerator (|s_w|<<1)
  }
  __syncthreads();

  // ---- ro phase: per wave 16 rows; chunk c = head, d = c*256 + lane*4
  float ssum[16], ssq[16];
#pragma unroll
  for (int rw = 0; rw < 16; ++rw) { ssum[rw] = 0.f; ssq[rw] = 0.f; }
#pragma unroll
  for (int c = 0; c < 8; ++c) {
    int d0 = c * 256 + lane * 4;
    f32x4 vv[8];
#pragma unroll
    for (int kk = 0; kk < 8; ++kk) vv[kk] = *(const f32x4*)(vbuf + kk * D_ + d0);
#pragma unroll
    for (int rw = 0; rw < 16; ++rw) {
      bf16x8 at = *(const bf16x8*)&attnL[(wave * 16 + rw) * 64 + c * 8];
      f32x4 ro = (float)at[0] * vv[0] + (float)at[1] * vv[1] +
                 (float)at[2] * vv[2] + (float)at[3] * vv[3] +
                 (float)at[4] * vv[4] + (float)at[5] * vv[5] +
                 (float)at[6] * vv[6] + (float)at[7] * vv[7];
      ssum[rw] += ro[0] + ro[1] + ro[2] + ro[3];
      ssq[rw] += ro[0] * ro[0] + ro[1] * ro[1] + ro[2] * ro[2] + ro[3] * ro[3];
      ushort4 o = {f2bf(ro[0]), f2bf(ro[1]), f2bf(ro[2]), f2bf(ro[3])};
      *(ushort4*)(Xhat + (size_t)(row0 + wave * 16 + rw) * D_ + d0) = o;
    }
  }
  // per-row LN stats
  float muv = 0.f, rstdv = 0.f;
#pragma unroll
  for (int rw = 0; rw < 16; ++rw) {
    float s = ssum[rw], q = ssq[rw];
#pragma unroll
    for (int off = 1; off < 64; off <<= 1) {
      s += __shfl_xor(s, off, 64);
      q += __shfl_xor(q, off, 64);
    }
    float m = s * (1.f / 2048.f);
    float var = q * (1.f / 2048.f) - m * m;
    float rs = rsqrtf(var + 1e-5f);
    if (lane == rw) { muv = m; rstdv = rs; }
  }
  if (lane < 16) {
    mu_out[row0 + wave * 16 + lane] = muv;
    rstd_out[row0 + wave * 16 + lane] = rstdv;
  }
  __syncthreads();

  // ---- u-partials: wave owns 512-wide d-range, 8-row load strips
  for (int dt = 0; dt < 2; ++dt) {
    int d0 = wave * 512 + dt * 256 + lane * 4;
    f32x4 ua[8];
#pragma unroll
    for (int kk = 0; kk < 8; ++kk) ua[kk] = (f32x4){0.f, 0.f, 0.f, 0.f};
    for (int r8 = 0; r8 < 64; r8 += 8) {
      f32x4 hv[8];
#pragma unroll
      for (int q = 0; q < 8; ++q)
        hv[q] = *(const f32x4*)(hidden + (size_t)(row0 + r8 + q) * D_ + d0);
#pragma unroll
      for (int q = 0; q < 8; ++q) {
        f32x4 e0 = *(const f32x4*)&e8lds[r8 + q][0];
        f32x4 e1 = *(const f32x4*)&e8lds[r8 + q][4];
        ua[0] += e0[0] * hv[q]; ua[1] += e0[1] * hv[q];
        ua[2] += e0[2] * hv[q]; ua[3] += e0[3] * hv[q];
        ua[4] += e1[0] * hv[q]; ua[5] += e1[1] * hv[q];
        ua[6] += e1[2] * hv[q]; ua[7] += e1[3] * hv[q];
      }
    }
#pragma unroll
    for (int kk = 0; kk < 8; ++kk)
      *(f32x4*)(upart + ((size_t)blockIdx.x * 8 + kk) * D_ + d0) = ua[kk];
  }
  if (tid < 8) {
    float z = 0.f;
    for (int r = 0; r < 64; ++r) z += e8lds[r][tid];
    Zpart[blockIdx.x * 8 + tid] = z;
  }
}

// ---- K4: reduce u-partials, t = u/Z  ([8][2048])
__global__ __launch_bounds__(256) void k_ured(const float* __restrict__ upart,
                                              const float* __restrict__ Zpart,
                                              float* __restrict__ tbuf) {
  int g = blockIdx.x * 256 + threadIdx.x;  // 0..16383
  int kk = g >> 11, d = g & 2047;
  float z = 0.f;
  for (int b = 0; b < 256; ++b) z += Zpart[b * 8 + kk];
  float u = 0.f;
  for (int b = 0; b < 256; ++b) u += upart[((size_t)b * 8 + kk) * 2048 + d];
  tbuf[g] = u / z;
}

// ---- K5b: new_memory = (1-wg)*memory + wg * (t @ Wwv.T)
__global__ __launch_bounds__(256) void k_newmem(
    const float* __restrict__ tbuf, const float* __restrict__ wwv,
    const float* __restrict__ mem, const float* __restrict__ wgate,
    float* __restrict__ out_mem) {
  int j = (blockIdx.x * 256 + threadIdx.x) >> 6;  // 0..2047
  int lane = threadIdx.x & 63;
  const f32x4* Wrow = (const f32x4*)(wwv + (size_t)j * D_);
  const f32x4* T4 = (const f32x4*)tbuf;
  float acc[8];
#pragma unroll
  for (int kk = 0; kk < 8; ++kk) acc[kk] = 0.f;
#pragma unroll
  for (int t = 0; t < 8; ++t) {
    f32x4 w4 = Wrow[lane + 64 * t];
#pragma unroll
    for (int kk = 0; kk < 8; ++kk) {
      f32x4 t4 = T4[kk * 512 + lane + 64 * t];
      acc[kk] += w4[0] * t4[0] + w4[1] * t4[1] + w4[2] * t4[2] + w4[3] * t4[3];
    }
  }
#pragma unroll
  for (int off = 1; off < 64; off <<= 1)
#pragma unroll
    for (int kk = 0; kk < 8; ++kk) acc[kk] += __shfl_xor(acc[kk], off, 64);
  if (lane == 0) {
    float wg = 1.f / (1.f + __expf(-wgate[0]));
#pragma unroll
    for (int kk = 0; kk < 8; ++kk)
      out_mem[kk * D_ + j] = (1.f - wg) * mem[kk * D_ + j] + wg * acc[kk];
  }
}

// ---- K5: result = hidden + g*(rstd*(ro@W'^T) - rstd*mu*c1 + c2)   bf16 MFMA 128x128
__global__ __launch_bounds__(256) void k_gemm(
    const unsigned short* __restrict__ A,  // raw ro bf16 [16384][2048]
    const unsigned short* __restrict__ B,  // W' bf16 [2048][2048] (row j = out col)
    const float* __restrict__ hidden, const float* __restrict__ gate,
    const float* __restrict__ mu, const float* __restrict__ rstd,
    const float* __restrict__ c1, const float* __restrict__ c2,
    float* __restrict__ out) {
  __shared__ unsigned short As[2][128 * 64];
  __shared__ unsigned short Bs[2][128 * 64];
  const int tid = threadIdx.x;
  int wg = blockIdx.x;
  int swz = (wg & 7) * 256 + (wg >> 3);  // XCD-contiguous: same A-panel stays on one XCD
  const int bm = swz >> 4, bn = swz & 15;
  const int row0 = bm * 128, col0 = bn * 128;
  const int wave = tid >> 6, lane = tid & 63;
  const int wr = wave >> 1, wc = wave & 1;
  const int fl = lane & 15, fk = lane >> 4;
  const int srow = tid >> 3, scol = (tid & 7) * 8;

  f32x4 acc[4][4];
#pragma unroll
  for (int m = 0; m < 4; ++m)
#pragma unroll
    for (int n = 0; n < 4; ++n) acc[m][n] = (f32x4){0.f, 0.f, 0.f, 0.f};

  auto stage = [&](int buf, int kt) {
    const int k0 = kt * 64;
#pragma unroll
    for (int p = 0; p < 4; ++p) {
      int r = srow + p * 32;
      lds_load16(&As[buf][r * 64 + scol], A + (size_t)(row0 + r) * D_ + k0 + scol);
      lds_load16(&Bs[buf][r * 64 + scol], B + (size_t)(col0 + r) * D_ + k0 + scol);
    }
  };

  stage(0, 0);
  for (int kt = 0; kt < 32; ++kt) {
    __syncthreads();
    if (kt + 1 < 32) stage((kt + 1) & 1, kt + 1);
    const int cb = kt & 1;
#pragma unroll
    for (int kkk = 0; kkk < 2; ++kkk) {
      bf16x8 af[4], bfr[4];
#pragma unroll
      for (int m = 0; m < 4; ++m)
        af[m] = *(const bf16x8*)&As[cb][(wr * 64 + m * 16 + fl) * 64 + kkk * 32 + fk * 8];
#pragma unroll
      for (int n = 0; n < 4; ++n)
        bfr[n] = *(const bf16x8*)&Bs[cb][(wc * 64 + n * 16 + fl) * 64 + kkk * 32 + fk * 8];
#pragma unroll
      for (int m = 0; m < 4; ++m)
#pragma unroll
        for (int n = 0; n < 4; ++n)
          acc[m][n] = __builtin_amdgcn_mfma_f32_16x16x32_bf16(af[m], bfr[n], acc[m][n], 0, 0, 0);
    }
  }
  float g = 1.f / (1.f + __expf(-gate[0]));
#pragma unroll
  for (int n = 0; n < 4; ++n) {
    int col = col0 + wc * 64 + n * 16 + fl;
    float C1 = c1[col] * g, C2 = c2[col] * g;
#pragma unroll
    for (int m = 0; m < 4; ++m)
#pragma unroll
      for (int r = 0; r < 4; ++r) {
        int row = row0 + wr * 64 + m * 16 + fk * 4 + r;
        float RS = rstd[row], MU = mu[row];
        size_t idx = (size_t)row * D_ + col;
        out[idx] = hidden[idx] + g * RS * acc[m][n][r] - RS * MU * C1 + C2;
      }
  }
}

extern "C" void kernel_launch(void* const* d_in, const int* in_sizes, int n_in,
                              void* d_out, int out_size, void* d_ws, size_t ws_size,
                              hipStream_t stream) {
  const float* hidden = (const float*)d_in[0];
  const float* mem    = (const float*)d_in[1];
  const float* wrq = (const float*)d_in[2];
  const float* wrk = (const float*)d_in[3];
  const float* wrv = (const float*)d_in[4];
  const float* wro = (const float*)d_in[5];
  const float* wwq = (const float*)d_in[6];
  const float* wwk = (const float*)d_in[7];
  const float* wwv = (const float*)d_in[8];
  const float* gamma = (const float*)d_in[9];
  const float* beta  = (const float*)d_in[10];
  const float* gate  = (const float*)d_in[11];
  const float* wgate = (const float*)d_in[12];
  float* out = (float*)d_out;

  char* ws = (char*)d_ws;
  float* kbuf  = (float*)(ws);                    // 64 KB; reused as mu after k_pr
  float* vbuf  = (float*)(ws + (64 << 10));       // 64 KB
  float* wqbuf = (float*)(ws + (128 << 10));      // 64 KB; reused as rstd after k_pr
  float* PRT   = (float*)(ws + (192 << 10));      // 640 KB fp32
  float* tbuf  = (float*)(ws + (832 << 10));      // 64 KB
  float* Zpart = (float*)(ws + (896 << 10));      // 8 KB
  float* c1    = (float*)(ws + (904 << 10));      // 8 KB
  float* c2    = (float*)(ws + (912 << 10));      // 8 KB
  float* upart = (float*)(ws + (960ull << 10));   // 16 MB
  unsigned short* Wp   = (unsigned short*)(ws + (960ull << 10) + (16ull << 20));  // 8 MB
  unsigned short* Xhat = (unsigned short*)(ws + (960ull << 10) + (24ull << 20));  // 64 MB
  float* mu   = kbuf;    // overlay: kbuf dead after k_pr
  float* rstd = wqbuf;   // overlay: wqbuf dead after k_pr

  hipMemsetAsync(PRT, 0, 80 * 2048 * sizeof(float), stream);
  k_cvtw<<<2048, 256, 0, stream>>>(wro, gamma, Wp);
  k_wsum<<<512, 256, 0, stream>>>(wro, gamma, beta, c1, c2);
  k_kvwq<<<1536, 256, 0, stream>>>(mem, wrk, wrv, wwq, kbuf, vbuf, wqbuf);
  k_pr<<<128, 256, 0, stream>>>(wrq, wwk, kbuf, wqbuf, PRT);
  k_main<<<256, 256, 0, stream>>>(hidden, PRT, vbuf, Xhat, mu, rstd, upart, Zpart);
  k_ured<<<64, 256, 0, stream>>>(upart, Zpart, tbuf);
  k_newmem<<<512, 256, 0, stream>>>(tbuf, wwv, mem, wgate, out + (size_t)N_ * D_);
  k_gemm<<<2048, 256, 0, stream>>>(Xhat, Wp, hidden, gate, mu, rstd, c1, c2, out);
}

// Round 4
// 438.576 us; speedup vs baseline: 1.2837x; 1.2837x over previous
//
#include <hip/hip_runtime.h>
#include <hip/hip_bf16.h>
#include <stdint.h>

static constexpr int N_ = 16384;
static constexpr int D_ = 2048;
static constexpr float SCALE_R = 1.0f / 16.0f;            // 1/sqrt(HD=256)
static constexpr float SCALE_W = 0.02209708691207961f;    // 1/sqrt(D=2048)

typedef __bf16 bf16x8 __attribute__((ext_vector_type(8)));
typedef float f32x4 __attribute__((ext_vector_type(4)));

__device__ __forceinline__ unsigned short f2bf(float f) {
  unsigned int u = __float_as_uint(f);
  unsigned int r = (u + 0x7fff + ((u >> 16) & 1)) >> 16;  // RNE
  return (unsigned short)r;
}

__device__ __forceinline__ void lds_load16(void* lds, const void* g) {
  __builtin_amdgcn_global_load_lds(
      (const __attribute__((address_space(1))) uint32_t*)(uintptr_t)g,
      (__attribute__((address_space(3))) uint32_t*)(uint32_t)(uintptr_t)lds,
      16, 0, 0);
}

// ---- K1: k = memory@Wrk.T, v = memory@Wrv.T, wq = memory@Wwq.T  (each [8][2048])
__global__ __launch_bounds__(256) void k_kvwq(
    const float* __restrict__ mem, const float* __restrict__ wrk,
    const float* __restrict__ wrv, const float* __restrict__ wwq,
    float* __restrict__ kbuf, float* __restrict__ vbuf, float* __restrict__ wqbuf) {
  int gw = (blockIdx.x * 256 + threadIdx.x) >> 6;  // 0..6143
  int lane = threadIdx.x & 63;
  int which = gw >> 11;
  int j = gw & 2047;
  const float* W = which == 0 ? wrk : (which == 1 ? wrv : wwq);
  float* O = which == 0 ? kbuf : (which == 1 ? vbuf : wqbuf);
  const f32x4* Wrow = (const f32x4*)(W + (size_t)j * D_);
  const f32x4* M4 = (const f32x4*)mem;
  float acc[8];
#pragma unroll
  for (int kk = 0; kk < 8; ++kk) acc[kk] = 0.f;
#pragma unroll
  for (int t = 0; t < 8; ++t) {
    f32x4 w4 = Wrow[lane + 64 * t];
#pragma unroll
    for (int kk = 0; kk < 8; ++kk) {
      f32x4 m4 = M4[kk * 512 + lane + 64 * t];
      acc[kk] += w4[0] * m4[0] + w4[1] * m4[1] + w4[2] * m4[2] + w4[3] * m4[3];
    }
  }
#pragma unroll
  for (int off = 1; off < 64; off <<= 1)
#pragma unroll
    for (int kk = 0; kk < 8; ++kk) acc[kk] += __shfl_xor(acc[kk], off, 64);
  if (lane == 0) {
#pragma unroll
    for (int kk = 0; kk < 8; ++kk) O[kk * D_ + j] = acc[kk];
  }
}

// ---- K2: PRT[80][2048] fp32: rows 0..63 = P (scaled 1/16), rows 64..71 = R
__global__ __launch_bounds__(256) void k_pr(
    const float* __restrict__ wrq, const float* __restrict__ wwk,
    const float* __restrict__ kbuf, const float* __restrict__ wqbuf,
    float* __restrict__ PRT) {
  int b = blockIdx.x;
  int tid = threadIdx.x;
  if (b < 64) {
    int ic = b >> 3, h = b & 7;
    int i = ic * 256 + tid;
    float acc[8];
#pragma unroll
    for (int kk = 0; kk < 8; ++kk) acc[kk] = 0.f;
    for (int jj = 0; jj < 256; ++jj) {
      int j = h * 256 + jj;
      float wv = wrq[(size_t)j * D_ + i];
#pragma unroll
      for (int kk = 0; kk < 8; ++kk) acc[kk] += wv * kbuf[kk * D_ + j];
    }
#pragma unroll
    for (int kk = 0; kk < 8; ++kk) PRT[(h * 8 + kk) * D_ + i] = acc[kk] * SCALE_R;
  } else {
    int bb = b - 64;
    int ic = bb >> 3, jc = bb & 7;
    int i = ic * 256 + tid;
    float acc[8];
#pragma unroll
    for (int kk = 0; kk < 8; ++kk) acc[kk] = 0.f;
    for (int jj = 0; jj < 256; ++jj) {
      int j = jc * 256 + jj;
      float wv = wwk[(size_t)j * D_ + i];
#pragma unroll
      for (int kk = 0; kk < 8; ++kk) acc[kk] += wv * wqbuf[kk * D_ + j];
    }
#pragma unroll
    for (int kk = 0; kk < 8; ++kk) atomicAdd(&PRT[(64 + kk) * D_ + i], acc[kk] * SCALE_W);
  }
}

// ---- W' = gamma ⊙ Wout rows -> bf16 (one row per block)
__global__ __launch_bounds__(256) void k_cvtw(const float* __restrict__ wro,
                                              const float* __restrict__ gamma,
                                              unsigned short* __restrict__ wp) {
  int j = blockIdx.x;
  int d = threadIdx.x * 8;
  const float* src = wro + (size_t)j * D_ + d;
  f32x4 a = *(const f32x4*)src, b = *(const f32x4*)(src + 4);
  f32x4 g0 = *(const f32x4*)(gamma + d), g1 = *(const f32x4*)(gamma + d + 4);
  ushort4 o0, o1;
  o0.x = f2bf(a[0] * g0[0]); o0.y = f2bf(a[1] * g0[1]);
  o0.z = f2bf(a[2] * g0[2]); o0.w = f2bf(a[3] * g0[3]);
  o1.x = f2bf(b[0] * g1[0]); o1.y = f2bf(b[1] * g1[1]);
  o1.z = f2bf(b[2] * g1[2]); o1.w = f2bf(b[3] * g1[3]);
  unsigned short* dst = wp + (size_t)j * D_ + d;
  *(ushort4*)dst = o0;
  *(ushort4*)(dst + 4) = o1;
}

// ---- c1[j] = sum_d gamma[d]*W[j][d], c2[j] = sum_d beta[d]*W[j][d]
__global__ __launch_bounds__(256) void k_wsum(const float* __restrict__ wro,
                                              const float* __restrict__ gamma,
                                              const float* __restrict__ beta,
                                              float* __restrict__ c1, float* __restrict__ c2) {
  int wave = threadIdx.x >> 6, lane = threadIdx.x & 63;
  int j = blockIdx.x * 4 + wave;
  const float* row = wro + (size_t)j * D_;
  float s1 = 0.f, s2 = 0.f;
#pragma unroll
  for (int t = 0; t < 8; ++t) {
    int d = t * 256 + lane * 4;
    f32x4 w = *(const f32x4*)(row + d);
    f32x4 g = *(const f32x4*)(gamma + d);
    f32x4 b = *(const f32x4*)(beta + d);
    s1 += w[0] * g[0] + w[1] * g[1] + w[2] * g[2] + w[3] * g[3];
    s2 += w[0] * b[0] + w[1] * b[1] + w[2] * b[2] + w[3] * b[3];
  }
#pragma unroll
  for (int off = 1; off < 64; off <<= 1) {
    s1 += __shfl_xor(s1, off, 64);
    s2 += __shfl_xor(s2, off, 64);
  }
  if (lane == 0) { c1[j] = s1; c2[j] = s2; }
}

// ---- K3: fused MFMA S-GEMM + in-reg PER-HEAD softmax + ro + (raw ro, mu, rstd) + u-partials
__global__ __launch_bounds__(256) void k_main(
    const float* __restrict__ hidden, const float* __restrict__ PRT,
    const float* __restrict__ vbuf,
    unsigned short* __restrict__ Xhat, float* __restrict__ mu_out,
    float* __restrict__ rstd_out,
    float* __restrict__ upart, float* __restrict__ Zpart) {
  __shared__ unsigned short Ah[2][64 * 64];   // 16 KB, XOR-swizzled bf16 hidden tile
  __shared__ unsigned short Bh[2][80 * 64];   // 20 KB, XOR-swizzled bf16 PRT tile
  __shared__ unsigned short attnL[64 * 64];   // 8 KB bf16 attn
  __shared__ float e8lds[64][8];              // 2 KB
  const int tid = threadIdx.x;
  const int row0 = blockIdx.x * 64;
  const int wave = tid >> 6, lane = tid & 63;
  const int fl = lane & 15, fk = lane >> 4;
  const int ar = tid >> 2, acg = tid & 3;     // A staging: row, 16-col group

  f32x4 sA0[4], sB0[5], sA1[4], sB1[5];

  auto loadAB = [&](f32x4* a, f32x4* b, int t) {
    const float* srcA = hidden + (size_t)(row0 + ar) * D_ + t * 64 + acg * 16;
#pragma unroll
    for (int q = 0; q < 4; ++q) a[q] = *(const f32x4*)(srcA + q * 4);
#pragma unroll
    for (int p = 0; p < 5; ++p) {
      int e = p * 256 + tid;
      int rB = e >> 4, c4 = e & 15;
      b[p] = *(const f32x4*)(PRT + (size_t)rB * D_ + t * 64 + c4 * 4);
    }
  };
  auto writeAB = [&](int buf, f32x4* a, f32x4* b) {
#pragma unroll
    for (int hh = 0; hh < 2; ++hh) {
      f32x4 x = a[hh * 2], y = a[hh * 2 + 1];
      ushort4 o0 = {f2bf(x[0]), f2bf(x[1]), f2bf(x[2]), f2bf(x[3])};
      ushort4 o1 = {f2bf(y[0]), f2bf(y[1]), f2bf(y[2]), f2bf(y[3])};
      int idx = (ar * 64 + acg * 16 + hh * 8) ^ ((ar & 7) << 3);
      *(ushort4*)&Ah[buf][idx] = o0;
      *(ushort4*)&Ah[buf][idx + 4] = o1;
    }
#pragma unroll
    for (int p = 0; p < 5; ++p) {
      int e = p * 256 + tid;
      int rB = e >> 4, c4 = e & 15;
      ushort4 o = {f2bf(b[p][0]), f2bf(b[p][1]), f2bf(b[p][2]), f2bf(b[p][3])};
      int idx = (rB * 64 + c4 * 4) ^ ((rB & 7) << 3);
      *(ushort4*)&Bh[buf][idx] = o;
    }
  };

  f32x4 acc[5];
#pragma unroll
  for (int n = 0; n < 5; ++n) acc[n] = (f32x4){0.f, 0.f, 0.f, 0.f};

  auto compute = [&](int buf) {
#pragma unroll
    for (int kk = 0; kk < 2; ++kk) {
      int klo = kk * 32 + fk * 8;
      bf16x8 af = *(const bf16x8*)&Ah[buf][((wave * 16 + fl) * 64 + klo) ^ ((fl & 7) << 3)];
#pragma unroll
      for (int n = 0; n < 5; ++n) {
        bf16x8 bf = *(const bf16x8*)&Bh[buf][((n * 16 + fl) * 64 + klo) ^ ((fl & 7) << 3)];
        acc[n] = __builtin_amdgcn_mfma_f32_16x16x32_bf16(af, bf, acc[n], 0, 0, 0);
      }
    }
  };

  loadAB(sA0, sB0, 0);
  loadAB(sA1, sB1, 1);
  for (int t = 0; t < 32; t += 2) {
    writeAB(0, sA0, sB0);
    if (t + 2 < 32) loadAB(sA0, sB0, t + 2);
    __syncthreads();
    compute(0);
    writeAB(1, sA1, sB1);
    if (t + 3 < 32) loadAB(sA1, sB1, t + 3);
    __syncthreads();
    compute(1);
  }

  // ---- in-register PER-HEAD softmax.
  // acc[n][r] = S[row=wave*16+fk*4+r][col=n*16+fl]; head = col>>3 lives in one
  // 8-lane half of one reg n -> reduce with xor 1,2,4 only (stays in the half).
#pragma unroll
  for (int r = 0; r < 4; ++r) {
    int rowl = wave * 16 + fk * 4 + r;
#pragma unroll
    for (int n = 0; n < 4; ++n) {
      float sv = acc[n][r];
      float m = sv;
      m = fmaxf(m, __shfl_xor(m, 1, 64));
      m = fmaxf(m, __shfl_xor(m, 2, 64));
      m = fmaxf(m, __shfl_xor(m, 4, 64));
      float e = __expf(sv - m);
      float ssum = e;
      ssum += __shfl_xor(ssum, 1, 64);
      ssum += __shfl_xor(ssum, 2, 64);
      ssum += __shfl_xor(ssum, 4, 64);
      attnL[rowl * 64 + n * 16 + fl] = f2bf(e / ssum);
    }
    if (fl < 8) e8lds[rowl][fl] = __expf(acc[4][r]);  // write-softmax numerator (|s_w|<<1)
  }
  __syncthreads();

  // ---- ro phase: per wave 16 rows; chunk c = head, d = c*256 + lane*4
  float ssum[16], ssq[16];
#pragma unroll
  for (int rw = 0; rw < 16; ++rw) { ssum[rw] = 0.f; ssq[rw] = 0.f; }
#pragma unroll
  for (int c = 0; c < 8; ++c) {
    int d0 = c * 256 + lane * 4;
    f32x4 vv[8];
#pragma unroll
    for (int kk = 0; kk < 8; ++kk) vv[kk] = *(const f32x4*)(vbuf + kk * D_ + d0);
#pragma unroll
    for (int rw = 0; rw < 16; ++rw) {
      bf16x8 at = *(const bf16x8*)&attnL[(wave * 16 + rw) * 64 + c * 8];
      f32x4 ro = (float)at[0] * vv[0] + (float)at[1] * vv[1] +
                 (float)at[2] * vv[2] + (float)at[3] * vv[3] +
                 (float)at[4] * vv[4] + (float)at[5] * vv[5] +
                 (float)at[6] * vv[6] + (float)at[7] * vv[7];
      ssum[rw] += ro[0] + ro[1] + ro[2] + ro[3];
      ssq[rw] += ro[0] * ro[0] + ro[1] * ro[1] + ro[2] * ro[2] + ro[3] * ro[3];
      ushort4 o = {f2bf(ro[0]), f2bf(ro[1]), f2bf(ro[2]), f2bf(ro[3])};
      *(ushort4*)(Xhat + (size_t)(row0 + wave * 16 + rw) * D_ + d0) = o;
    }
  }
  // per-row LN stats
  float muv = 0.f, rstdv = 0.f;
#pragma unroll
  for (int rw = 0; rw < 16; ++rw) {
    float s = ssum[rw], q = ssq[rw];
#pragma unroll
    for (int off = 1; off < 64; off <<= 1) {
      s += __shfl_xor(s, off, 64);
      q += __shfl_xor(q, off, 64);
    }
    float m = s * (1.f / 2048.f);
    float var = q * (1.f / 2048.f) - m * m;
    float rs = rsqrtf(var + 1e-5f);
    if (lane == rw) { muv = m; rstdv = rs; }
  }
  if (lane < 16) {
    mu_out[row0 + wave * 16 + lane] = muv;
    rstd_out[row0 + wave * 16 + lane] = rstdv;
  }
  __syncthreads();

  // ---- u-partials: wave owns 512-wide d-range, 8-row load strips
  for (int dt = 0; dt < 2; ++dt) {
    int d0 = wave * 512 + dt * 256 + lane * 4;
    f32x4 ua[8];
#pragma unroll
    for (int kk = 0; kk < 8; ++kk) ua[kk] = (f32x4){0.f, 0.f, 0.f, 0.f};
    for (int r8 = 0; r8 < 64; r8 += 8) {
      f32x4 hv[8];
#pragma unroll
      for (int q = 0; q < 8; ++q)
        hv[q] = *(const f32x4*)(hidden + (size_t)(row0 + r8 + q) * D_ + d0);
#pragma unroll
      for (int q = 0; q < 8; ++q) {
        f32x4 e0 = *(const f32x4*)&e8lds[r8 + q][0];
        f32x4 e1 = *(const f32x4*)&e8lds[r8 + q][4];
        ua[0] += e0[0] * hv[q]; ua[1] += e0[1] * hv[q];
        ua[2] += e0[2] * hv[q]; ua[3] += e0[3] * hv[q];
        ua[4] += e1[0] * hv[q]; ua[5] += e1[1] * hv[q];
        ua[6] += e1[2] * hv[q]; ua[7] += e1[3] * hv[q];
      }
    }
#pragma unroll
    for (int kk = 0; kk < 8; ++kk)
      *(f32x4*)(upart + ((size_t)blockIdx.x * 8 + kk) * D_ + d0) = ua[kk];
  }
  if (tid < 8) {
    float z = 0.f;
    for (int r = 0; r < 64; ++r) z += e8lds[r][tid];
    Zpart[blockIdx.x * 8 + tid] = z;
  }
}

// ---- K4: reduce u-partials, t = u/Z  ([8][2048])
__global__ __launch_bounds__(256) void k_ured(const float* __restrict__ upart,
                                              const float* __restrict__ Zpart,
                                              float* __restrict__ tbuf) {
  int g = blockIdx.x * 256 + threadIdx.x;  // 0..16383
  int kk = g >> 11, d = g & 2047;
  float z = 0.f;
  for (int b = 0; b < 256; ++b) z += Zpart[b * 8 + kk];
  float u = 0.f;
  for (int b = 0; b < 256; ++b) u += upart[((size_t)b * 8 + kk) * 2048 + d];
  tbuf[g] = u / z;
}

// ---- K5b: new_memory = (1-wg)*memory + wg * (t @ Wwv.T)
__global__ __launch_bounds__(256) void k_newmem(
    const float* __restrict__ tbuf, const float* __restrict__ wwv,
    const float* __restrict__ mem, const float* __restrict__ wgate,
    float* __restrict__ out_mem) {
  int j = (blockIdx.x * 256 + threadIdx.x) >> 6;  // 0..2047
  int lane = threadIdx.x & 63;
  const f32x4* Wrow = (const f32x4*)(wwv + (size_t)j * D_);
  const f32x4* T4 = (const f32x4*)tbuf;
  float acc[8];
#pragma unroll
  for (int kk = 0; kk < 8; ++kk) acc[kk] = 0.f;
#pragma unroll
  for (int t = 0; t < 8; ++t) {
    f32x4 w4 = Wrow[lane + 64 * t];
#pragma unroll
    for (int kk = 0; kk < 8; ++kk) {
      f32x4 t4 = T4[kk * 512 + lane + 64 * t];
      acc[kk] += w4[0] * t4[0] + w4[1] * t4[1] + w4[2] * t4[2] + w4[3] * t4[3];
    }
  }
#pragma unroll
  for (int off = 1; off < 64; off <<= 1)
#pragma unroll
    for (int kk = 0; kk < 8; ++kk) acc[kk] += __shfl_xor(acc[kk], off, 64);
  if (lane == 0) {
    float wg = 1.f / (1.f + __expf(-wgate[0]));
#pragma unroll
    for (int kk = 0; kk < 8; ++kk)
      out_mem[kk * D_ + j] = (1.f - wg) * mem[kk * D_ + j] + wg * acc[kk];
  }
}

// ---- K5: result = hidden + g*(rstd*(ro@W'^T) - rstd*mu*c1 + c2)   bf16 MFMA 128x128
// Identity block mapping (default wg%8 == bn%8 gives each XCD a 2-bn B slab ->
// B stays L2-resident; the R3 chunked swizzle thrashed B through L3, -170us).
// LDS XOR-swizzle (m173/m201): linear global_load_lds dest + pre-swizzled
// global source column + XOR'd ds_read address kills the 16-way bank conflict.
__global__ __launch_bounds__(256) void k_gemm(
    const unsigned short* __restrict__ A,  // raw ro bf16 [16384][2048]
    const unsigned short* __restrict__ B,  // W' bf16 [2048][2048] (row j = out col)
    const float* __restrict__ hidden, const float* __restrict__ gate,
    const float* __restrict__ mu, const float* __restrict__ rstd,
    const float* __restrict__ c1, const float* __restrict__ c2,
    float* __restrict__ out) {
  __shared__ unsigned short As[2][128 * 64];
  __shared__ unsigned short Bs[2][128 * 64];
  const int tid = threadIdx.x;
  const int bm = blockIdx.x >> 4, bn = blockIdx.x & 15;
  const int row0 = bm * 128, col0 = bn * 128;
  const int wave = tid >> 6, lane = tid & 63;
  const int wr = wave >> 1, wc = wave & 1;
  const int fl = lane & 15, fk = lane >> 4;
  const int srow = tid >> 3;
  const int cg = (tid & 7) ^ (srow & 7);   // pre-swizzled source col granule (16B)
  const int scol_l = (tid & 7) * 8;        // linear LDS dest col (ushorts)
  const int scol_g = cg * 8;               // swizzled global col (ushorts)

  f32x4 acc[4][4];
#pragma unroll
  for (int m = 0; m < 4; ++m)
#pragma unroll
    for (int n = 0; n < 4; ++n) acc[m][n] = (f32x4){0.f, 0.f, 0.f, 0.f};

  auto stage = [&](int buf, int kt) {
    const int k0 = kt * 64;
#pragma unroll
    for (int p = 0; p < 4; ++p) {
      int r = srow + p * 32;  // (r&7) == (srow&7) since 32 ≡ 0 mod 8
      lds_load16(&As[buf][r * 64 + scol_l], A + (size_t)(row0 + r) * D_ + k0 + scol_g);
      lds_load16(&Bs[buf][r * 64 + scol_l], B + (size_t)(col0 + r) * D_ + k0 + scol_g);
    }
  };

  stage(0, 0);
  for (int kt = 0; kt < 32; ++kt) {
    __syncthreads();
    if (kt + 1 < 32) stage((kt + 1) & 1, kt + 1);
    const int cb = kt & 1;
#pragma unroll
    for (int kkk = 0; kkk < 2; ++kkk) {
      // row&7 == fl&7 for all fragment rows; granule G = kkk*4+fk
      const int gsw = ((kkk * 4 + fk) ^ (fl & 7)) * 8;
      bf16x8 af[4], bfr[4];
#pragma unroll
      for (int m = 0; m < 4; ++m)
        af[m] = *(const bf16x8*)&As[cb][(wr * 64 + m * 16 + fl) * 64 + gsw];
#pragma unroll
      for (int n = 0; n < 4; ++n)
        bfr[n] = *(const bf16x8*)&Bs[cb][(wc * 64 + n * 16 + fl) * 64 + gsw];
#pragma unroll
      for (int m = 0; m < 4; ++m)
#pragma unroll
        for (int n = 0; n < 4; ++n)
          acc[m][n] = __builtin_amdgcn_mfma_f32_16x16x32_bf16(af[m], bfr[n], acc[m][n], 0, 0, 0);
    }
  }
  float g = 1.f / (1.f + __expf(-gate[0]));
#pragma unroll
  for (int n = 0; n < 4; ++n) {
    int col = col0 + wc * 64 + n * 16 + fl;
    float C1 = c1[col] * g, C2 = c2[col] * g;
#pragma unroll
    for (int m = 0; m < 4; ++m)
#pragma unroll
      for (int r = 0; r < 4; ++r) {
        int row = row0 + wr * 64 + m * 16 + fk * 4 + r;
        float RS = rstd[row], MU = mu[row];
        size_t idx = (size_t)row * D_ + col;
        out[idx] = hidden[idx] + g * RS * acc[m][n][r] - RS * MU * C1 + C2;
      }
  }
}

extern "C" void kernel_launch(void* const* d_in, const int* in_sizes, int n_in,
                              void* d_out, int out_size, void* d_ws, size_t ws_size,
                              hipStream_t stream) {
  const float* hidden = (const float*)d_in[0];
  const float* mem    = (const float*)d_in[1];
  const float* wrq = (const float*)d_in[2];
  const float* wrk = (const float*)d_in[3];
  const float* wrv = (const float*)d_in[4];
  const float* wro = (const float*)d_in[5];
  const float* wwq = (const float*)d_in[6];
  const float* wwk = (const float*)d_in[7];
  const float* wwv = (const float*)d_in[8];
  const float* gamma = (const float*)d_in[9];
  const float* beta  = (const float*)d_in[10];
  const float* gate  = (const float*)d_in[11];
  const float* wgate = (const float*)d_in[12];
  float* out = (float*)d_out;

  char* ws = (char*)d_ws;
  float* kbuf  = (float*)(ws);                    // 64 KB; reused as mu after k_pr
  float* vbuf  = (float*)(ws + (64 << 10));       // 64 KB
  float* wqbuf = (float*)(ws + (128 << 10));      // 64 KB; reused as rstd after k_pr
  float* PRT   = (float*)(ws + (192 << 10));      // 640 KB fp32
  float* tbuf  = (float*)(ws + (832 << 10));      // 64 KB
  float* Zpart = (float*)(ws + (896 << 10));      // 8 KB
  float* c1    = (float*)(ws + (904 << 10));      // 8 KB
  float* c2    = (float*)(ws + (912 << 10));      // 8 KB
  float* upart = (float*)(ws + (960ull << 10));   // 16 MB
  unsigned short* Wp   = (unsigned short*)(ws + (960ull << 10) + (16ull << 20));  // 8 MB
  unsigned short* Xhat = (unsigned short*)(ws + (960ull << 10) + (24ull << 20));  // 64 MB
  float* mu   = kbuf;    // overlay: kbuf dead after k_pr
  float* rstd = wqbuf;   // overlay: wqbuf dead after k_pr

  hipMemsetAsync(PRT, 0, 80 * 2048 * sizeof(float), stream);
  k_cvtw<<<2048, 256, 0, stream>>>(wro, gamma, Wp);
  k_wsum<<<512, 256, 0, stream>>>(wro, gamma, beta, c1, c2);
  k_kvwq<<<1536, 256, 0, stream>>>(mem, wrk, wrv, wwq, kbuf, vbuf, wqbuf);
  k_pr<<<128, 256, 0, stream>>>(wrq, wwk, kbuf, wqbuf, PRT);
  k_main<<<256, 256, 0, stream>>>(hidden, PRT, vbuf, Xhat, mu, rstd, upart, Zpart);
  k_ured<<<64, 256, 0, stream>>>(upart, Zpart, tbuf);
  k_newmem<<<512, 256, 0, stream>>>(tbuf, wwv, mem, wgate, out + (size_t)N_ * D_);
  k_gemm<<<2048, 256, 0, stream>>>(Xhat, Wp, hidden, gate, mu, rstd, c1, c2, out);
}